// Round 1
// baseline (191.956 us; speedup 1.0000x reference)
//
#include <hip/hip_runtime.h>
#include <math.h>

// Problem constants (fixed by reference)
#define BATCH        32768
#define IN_CH        512
#define OUT_CH       1024
#define NP           17     // NUM_POINTS
#define NSTEP        3

// Each thread: 1 float4 of data (4 input channels) -> 8 output floats.
// Total float4s = 32768*512/4 = 4,194,304 = 16384 blocks * 256 threads.

__global__ __launch_bounds__(256) void mac_kernel(
    const float* __restrict__ data,
    const float* __restrict__ angles,
    const float* __restrict__ velocity,
    const float* __restrict__ attention,
    const float* __restrict__ coeffp,
    const float* __restrict__ biasp,
    float* __restrict__ out)
{
    // Interleaved {velocity[j], angles[j]} table in LDS.
    // 17 distinct float2 addrs over 32 banks -> at most 2-way conflict (free),
    // duplicate lane indices broadcast.
    __shared__ float2 tab[NP];
    const int tid = threadIdx.x;
    if (tid < NP) {
        tab[tid] = make_float2(velocity[tid], angles[tid]);
    }
    const float coeff = coeffp[0];
    const float bias  = biasp[0];
    __syncthreads();

    const int gid = blockIdx.x * 256 + tid;        // float4 index into data
    const float4 d4 = ((const float4*)data)[gid];
    float x[4] = {d4.x, d4.y, d4.z, d4.w};

    const float HALF_NP = 8.5f;                    // NUM_POINTS / 2
    const float INV3    = 0.33333333333333333f;    // 1/NUM_STEPS
    const float TWO     = 2.0f;

    #pragma unroll
    for (int s = 0; s < NSTEP; ++s) {
        #pragma unroll
        for (int k = 0; k < 4; ++k) {
            float dv = x[k];
            // tanh(d*coeff + bias) via exp: tanh(t) = (e^{2t}-1)/(e^{2t}+1)
            float t = fmaf(dv, coeff, bias);
            t = fminf(fmaxf(t, -15.0f), 15.0f);    // avoid inf/NaN; tanh saturates
            float u  = __expf(TWO * t);            // v_exp_f32 path
            float th = (u - 1.0f) * __builtin_amdgcn_rcpf(u + 1.0f);
            float index = fmaf(th, HALF_NP, 1.0f); // in (-7.5, 9.5)

            float fb = floorf(index);
            int   bgn = (int)fb;
            // Replicate reference exactly: end = floor(index + 1.0), NOT bgn+1.
            // (Rare binade-boundary rounding makes them differ; the reference is
            //  discontinuous there and we must land on the same side.)
            float fe  = floorf(index + 1.0f);
            int   end = (int)fe;
            // end < NP always (end <= 10), so the reference's `lt` clamp is dead.
            // Negative wrap (torch-style indexing):
            int ib = bgn + ((bgn >> 31) & NP);     // bgn<0 ? bgn+17 : bgn
            int ie = end + ((end >> 31) & NP);

            float pos = index - fb;
            float om  = 1.0f - pos;

            float2 tb = tab[ib];
            float2 te = tab[ie];
            float velo = fmaf(om, tb.x, pos * te.x);
            float ang  = fmaf(om, tb.y, pos * te.y);

            float sn = __sinf(ang);                // ang in [0, 2pi] -> no range issue
            float cs = __cosf(ang);
            // step = velo*cos + d*velo*sin = velo * (cos + d*sin)
            float stp = velo * fmaf(dv, sn, cs);
            x[k] = fmaf(stp, INV3, x[k]);
        }
    }

    // Output mapping: data element (b, c) -> out[b*1024 + 2c + {0,1}]
    // gid covers 4 consecutive c: c = c4*4 .. c4*4+3, out floats 8*c4 .. 8*c4+7
    const int b  = gid >> 7;          // gid / (512/4)
    const int c4 = gid & 127;
    const float4* attv = (const float4*)attention;
    const float4 a0 = attv[c4 * 2];
    const float4 a1 = attv[c4 * 2 + 1];

    float4 o0 = make_float4(a0.x * x[0], a0.y * x[0], a0.z * x[1], a0.w * x[1]);
    float4 o1 = make_float4(a1.x * x[2], a1.y * x[2], a1.z * x[3], a1.w * x[3]);

    float4* outv = (float4*)out;
    const int base = b * 256 + c4 * 2;            // float4 index into out
    outv[base]     = o0;
    outv[base + 1] = o1;
}

extern "C" void kernel_launch(void* const* d_in, const int* in_sizes, int n_in,
                              void* d_out, int out_size, void* d_ws, size_t ws_size,
                              hipStream_t stream) {
    const float* data      = (const float*)d_in[0];
    const float* angles    = (const float*)d_in[1];
    const float* velocity  = (const float*)d_in[2];
    const float* attention = (const float*)d_in[3];
    const float* coeff     = (const float*)d_in[4];
    const float* bias      = (const float*)d_in[5];
    float* out = (float*)d_out;

    const int total_f4 = BATCH * IN_CH / 4;       // 4,194,304
    const int block = 256;
    const int grid  = total_f4 / block;           // 16384
    mac_kernel<<<grid, block, 0, stream>>>(data, angles, velocity, attention,
                                           coeff, bias, out);
}